// Round 1
// baseline (447.675 us; speedup 1.0000x reference)
//
#include <hip/hip_runtime.h>

#define HH 128
#define WW 128
#define CC 64
#define OCC 128
#define NBATCH 4
#define NTAP 9
#define TJ 16

// ws layout (floats):
//   off  : [4][18][128][128] at 0         (1179648 floats)
//   wp_t : [64][18][9]       at 1179648   (10368 floats)
//   wt   : [576][128]        at 1190016   (73728 floats)
#define OFF_OFS 0
#define WPT_OFS 1179648
#define WT_OFS  1190016

__global__ void transpose_weights(const float* __restrict__ w_p,
                                  const float* __restrict__ w_conv,
                                  float* __restrict__ ws) {
    int idx = blockIdx.x * blockDim.x + threadIdx.x;
    if (idx < 10368) {
        // wp_t[c][n][tap] = w_p[n][c][tap]
        int c = idx / 162;
        int r = idx % 162;      // n*9 + tap
        int n = r / 9, tap = r % 9;
        ws[WPT_OFS + idx] = w_p[(n * CC + c) * 9 + tap];
    }
    int idx2 = idx - 10368;
    if (idx2 >= 0 && idx2 < 73728) {
        // wt[ck][o] = w_conv[o][ck],  ck = c*9 + kx*3 + ky
        int ck = idx2 >> 7, o = idx2 & 127;
        ws[WT_OFS + idx2] = w_conv[o * 576 + ck];
    }
}

__global__ __launch_bounds__(256) void offset_conv(
        const float* __restrict__ feat,
        const float* __restrict__ b_p,
        const float* __restrict__ wpt,   // [64][18][9]
        float* __restrict__ off) {       // [4][18][128][128]
    int lin = blockIdx.x * 256 + threadIdx.x;
    int j = lin & 127;
    int i = (lin >> 7) & 127;
    int b = lin >> 14;

    float acc[18];
#pragma unroll
    for (int n = 0; n < 18; ++n) acc[n] = b_p[n];

    const float* fb = feat + b * CC * HH * WW;
    const bool im1 = (i > 0), ip1 = (i < HH - 1);
    const bool jm1 = (j > 0), jp1 = (j < WW - 1);

    for (int c = 0; c < CC; ++c) {
        const float* fc = fb + c * HH * WW + i * WW + j;
        float f0 = (im1 && jm1) ? fc[-WW - 1] : 0.f;
        float f1 = im1          ? fc[-WW]     : 0.f;
        float f2 = (im1 && jp1) ? fc[-WW + 1] : 0.f;
        float f3 = jm1          ? fc[-1]      : 0.f;
        float f4 =                fc[0];
        float f5 = jp1          ? fc[1]       : 0.f;
        float f6 = (ip1 && jm1) ? fc[WW - 1]  : 0.f;
        float f7 = ip1          ? fc[WW]      : 0.f;
        float f8 = (ip1 && jp1) ? fc[WW + 1]  : 0.f;
        const float* wr = wpt + c * 162;   // wave-uniform -> s_load
#pragma unroll
        for (int n = 0; n < 18; ++n) {
            acc[n] = fmaf(f0, wr[n * 9 + 0], acc[n]);
            acc[n] = fmaf(f1, wr[n * 9 + 1], acc[n]);
            acc[n] = fmaf(f2, wr[n * 9 + 2], acc[n]);
            acc[n] = fmaf(f3, wr[n * 9 + 3], acc[n]);
            acc[n] = fmaf(f4, wr[n * 9 + 4], acc[n]);
            acc[n] = fmaf(f5, wr[n * 9 + 5], acc[n]);
            acc[n] = fmaf(f6, wr[n * 9 + 6], acc[n]);
            acc[n] = fmaf(f7, wr[n * 9 + 7], acc[n]);
            acc[n] = fmaf(f8, wr[n * 9 + 8], acc[n]);
        }
    }
    int sp = i * WW + j;
#pragma unroll
    for (int n = 0; n < 18; ++n)
        off[(b * 18 + n) * (HH * WW) + sp] = acc[n];
}

__global__ __launch_bounds__(128) void dcn_main(
        const float* __restrict__ feat,
        const float* __restrict__ b_conv,
        const float* __restrict__ off,   // [4][18][128][128]
        const float* __restrict__ wt,    // [576][128]
        float* __restrict__ out) {       // [4][128][128][128]
    __shared__ __align__(16) float xs[576 * TJ];   // x_off[ck][pos], 36864 B

    int bid = blockIdx.x;
    int jt = bid & 7;
    int i  = (bid >> 3) & 127;
    int b  = bid >> 10;
    int j0 = jt * TJ;
    int tid = threadIdx.x;

    // ---- phase 1: bilinear sampling into LDS ----
    for (int pair = tid; pair < NTAP * TJ; pair += 128) {
        int n = pair >> 4;       // tap 0..8
        int pos = pair & 15;
        int j = j0 + pos;
        int sp = i * WW + j;
        float offx = off[(b * 18 + n) * (HH * WW) + sp];
        float offy = off[(b * 18 + 9 + n) * (HH * WW) + sp];
        // p = p0 + p_n + offset ; p0 starts at 1, p_n = (n/3-1, n%3-1)
        float px = (float)(i + (n / 3)) + offx;
        float py = (float)(j + (n % 3)) + offy;
        float qxf = floorf(px), qyf = floorf(py);
        int x0 = min(max((int)qxf, 0), HH - 1);
        int y0 = min(max((int)qyf, 0), WW - 1);
        int x1 = min(max((int)qxf + 1, 0), HH - 1);
        int y1 = min(max((int)qyf + 1, 0), WW - 1);
        float pxc = fminf(fmaxf(px, 0.f), (float)(HH - 1));
        float pyc = fminf(fmaxf(py, 0.f), (float)(WW - 1));
        float gx0 = 1.f + ((float)x0 - pxc);
        float gx1 = 1.f - ((float)x1 - pxc);
        float gy0 = 1.f + ((float)y0 - pyc);
        float gy1 = 1.f - ((float)y1 - pyc);
        float glt = gx0 * gy0, grb = gx1 * gy1;
        float glb = gx0 * gy1, grt = gx1 * gy0;
        const float* fb = feat + b * CC * HH * WW;
        int o00 = x0 * WW + y0, o11 = x1 * WW + y1;
        int o01 = x0 * WW + y1, o10 = x1 * WW + y0;
#pragma unroll 4
        for (int c = 0; c < CC; ++c) {
            const float* fc = fb + c * HH * WW;
            float v = glt * fc[o00] + grb * fc[o11]
                    + glb * fc[o01] + grt * fc[o10];
            xs[(c * 9 + n) * TJ + pos] = v;
        }
    }
    __syncthreads();

    // ---- phase 2: out[o][pos] = sum_ck wt[ck][o] * xs[ck][pos] ----
    int ogrp = tid >> 2;          // 0..31
    int posg = tid & 3;           // 0..3
    int o0 = ogrp * 4;
    int p0 = posg * 4;

    float acc[4][4];
#pragma unroll
    for (int a = 0; a < 4; ++a)
#pragma unroll
        for (int d = 0; d < 4; ++d) acc[a][d] = 0.f;

    const float4* wt4 = (const float4*)wt;
#pragma unroll 4
    for (int ck = 0; ck < 576; ++ck) {
        float4 wv = wt4[(ck << 5) + ogrp];
        float4 xv = *(const float4*)&xs[(ck << 4) + p0];
        float wa[4] = {wv.x, wv.y, wv.z, wv.w};
        float xa[4] = {xv.x, xv.y, xv.z, xv.w};
#pragma unroll
        for (int a = 0; a < 4; ++a)
#pragma unroll
            for (int d = 0; d < 4; ++d)
                acc[a][d] = fmaf(wa[a], xa[d], acc[a][d]);
    }

#pragma unroll
    for (int a = 0; a < 4; ++a) {
        int o = o0 + a;
        float bc = b_conv[o];
        float4 r;
        r.x = acc[a][0] + bc;
        r.y = acc[a][1] + bc;
        r.z = acc[a][2] + bc;
        r.w = acc[a][3] + bc;
        *(float4*)&out[((b * OCC + o) * HH + i) * WW + j0 + p0] = r;
    }
}

extern "C" void kernel_launch(void* const* d_in, const int* in_sizes, int n_in,
                              void* d_out, int out_size, void* d_ws, size_t ws_size,
                              hipStream_t stream) {
    const float* feat   = (const float*)d_in[0];
    const float* w_p    = (const float*)d_in[1];
    const float* b_p    = (const float*)d_in[2];
    const float* w_conv = (const float*)d_in[3];
    const float* b_conv = (const float*)d_in[4];
    float* out = (float*)d_out;
    float* ws  = (float*)d_ws;

    float* off = ws + OFF_OFS;
    float* wpt = ws + WPT_OFS;
    float* wt  = ws + WT_OFS;

    hipLaunchKernelGGL(transpose_weights, dim3(329), dim3(256), 0, stream,
                       w_p, w_conv, ws);
    hipLaunchKernelGGL(offset_conv, dim3(256), dim3(256), 0, stream,
                       feat, b_p, wpt, off);
    hipLaunchKernelGGL(dcn_main, dim3(4096), dim3(128), 0, stream,
                       feat, b_conv, off, wt, out);
}

// Round 2
// 289.617 us; speedup vs baseline: 1.5457x; 1.5457x over previous
//
#include <hip/hip_runtime.h>
#include <hip/hip_bf16.h>

#define HH 128
#define WW 128
#define CC 64
#define OCC 128
#define NB 4
#define HW (HH * WW)

// ws layout (floats):
//   off  : [4][18][128][128] at 0         (1179648 floats)
//   wp_t : [64][18][9]       at 1179648   (10368 floats)
//   wt   : [576][128]        at 1190016   (73728 floats)
#define OFF_OFS 0
#define WPT_OFS 1179648
#define WT_OFS  1190016

__global__ void transpose_weights(const float* __restrict__ w_p,
                                  const float* __restrict__ w_conv,
                                  float* __restrict__ ws) {
    int idx = blockIdx.x * blockDim.x + threadIdx.x;
    if (idx < 10368) {
        // wp_t[c][n][tap] = w_p[n][c][tap]
        int c = idx / 162;
        int r = idx % 162;      // n*9 + tap
        int n = r / 9, tap = r % 9;
        ws[WPT_OFS + idx] = w_p[(n * CC + c) * 9 + tap];
    }
    int idx2 = idx - 10368;
    if (idx2 >= 0 && idx2 < 73728) {
        // wt[ck][o] = w_conv[o][ck],  ck = c*9 + kx*3 + ky
        int ck = idx2 >> 7, o = idx2 & 127;
        ws[WT_OFS + idx2] = w_conv[o * 576 + ck];
    }
}

// K-split 4-way: wave w handles channels [16w, 16w+16); LDS tree-reduce.
// Block = (b, i, jh): 64 consecutive j per block, lane = j offset.
__global__ __launch_bounds__(256) void offset_conv(
        const float* __restrict__ feat,
        const float* __restrict__ b_p,
        const float* __restrict__ wpt,   // [64][18][9]
        float* __restrict__ off) {       // [4][18][128][128]
    __shared__ float red[4][18][64];     // 18432 B

    int bid = blockIdx.x;                // (b*128 + i)*2 + jh
    int jh = bid & 1;
    int i  = (bid >> 1) & 127;
    int b  = bid >> 8;
    int tid = threadIdx.x;
    int lane = tid & 63;
    int w = tid >> 6;
    int j = jh * 64 + lane;
    int c0 = w * 16;

    float acc[18];
#pragma unroll
    for (int n = 0; n < 18; ++n) acc[n] = 0.f;

    const float* fb = feat + b * CC * HW;
    const bool im1 = (i > 0), ip1 = (i < HH - 1);
    const bool jm1 = (j > 0), jp1 = (j < WW - 1);

    for (int cc = 0; cc < 16; ++cc) {
        int c = c0 + cc;
        const float* fc = fb + c * HW + i * WW + j;
        float f0 = (im1 && jm1) ? fc[-WW - 1] : 0.f;
        float f1 = im1          ? fc[-WW]     : 0.f;
        float f2 = (im1 && jp1) ? fc[-WW + 1] : 0.f;
        float f3 = jm1          ? fc[-1]      : 0.f;
        float f4 =                fc[0];
        float f5 = jp1          ? fc[1]       : 0.f;
        float f6 = (ip1 && jm1) ? fc[WW - 1]  : 0.f;
        float f7 = ip1          ? fc[WW]      : 0.f;
        float f8 = (ip1 && jp1) ? fc[WW + 1]  : 0.f;
        const float* wr = wpt + c * 162;   // wave-uniform -> scalar loads
#pragma unroll
        for (int n = 0; n < 18; ++n) {
            acc[n] = fmaf(f0, wr[n * 9 + 0], acc[n]);
            acc[n] = fmaf(f1, wr[n * 9 + 1], acc[n]);
            acc[n] = fmaf(f2, wr[n * 9 + 2], acc[n]);
            acc[n] = fmaf(f3, wr[n * 9 + 3], acc[n]);
            acc[n] = fmaf(f4, wr[n * 9 + 4], acc[n]);
            acc[n] = fmaf(f5, wr[n * 9 + 5], acc[n]);
            acc[n] = fmaf(f6, wr[n * 9 + 6], acc[n]);
            acc[n] = fmaf(f7, wr[n * 9 + 7], acc[n]);
            acc[n] = fmaf(f8, wr[n * 9 + 8], acc[n]);
        }
    }
#pragma unroll
    for (int n = 0; n < 18; ++n) red[w][n][lane] = acc[n];
    __syncthreads();

    for (int it = tid; it < 18 * 64; it += 256) {
        int n = it >> 6, jj = it & 63;
        float v = b_p[n] + red[0][n][jj] + red[1][n][jj]
                         + red[2][n][jj] + red[3][n][jj];
        off[(b * 18 + n) * HW + i * WW + jh * 64 + jj] = v;
    }
}

// Block = 256 thr, tile = 64 positions (lane = pos). ck split into two
// halves of 288; xs staged as packed bf16 pairs (36864 B LDS).
// Wave w owns o-slice [32w, 32w+32): wt reads wave-uniform -> broadcast.
__global__ __launch_bounds__(256) void dcn_main(
        const float* __restrict__ feat,
        const float* __restrict__ b_conv,
        const float* __restrict__ off,   // [4][18][128][128]
        const float* __restrict__ wt,    // [576][128]
        float* __restrict__ out) {       // [4][128][128][128]
    __shared__ unsigned int xsp[144 * 64];   // bf16x2: (ckl pair) x pos, 36864 B

    int bid = blockIdx.x;                // (b*128 + i)*2 + jh
    int jh = bid & 1;
    int i  = (bid >> 1) & 127;
    int b  = bid >> 8;
    int j0 = jh * 64;
    int tid = threadIdx.x;
    int lane = tid & 63;
    int wu = __builtin_amdgcn_readfirstlane(tid >> 6);  // uniform wave id
    int o0 = wu * 32;

    float acc[32];
#pragma unroll
    for (int oo = 0; oo < 32; ++oo) acc[oo] = 0.f;

    const float* fb = feat + b * CC * HW;
    unsigned short* xs16 = (unsigned short*)xsp;

    for (int h = 0; h < 2; ++h) {
        // ---- phase 1: gather 32 channels x 9 taps into LDS (bf16) ----
        for (int item = tid; item < 576; item += 256) {
            int n = item >> 6;       // tap 0..8
            int pos = item & 63;
            int j = j0 + pos;
            int sp = i * WW + j;
            float offx = off[(b * 18 + n) * HW + sp];
            float offy = off[(b * 18 + 9 + n) * HW + sp];
            float px = (float)(i + (n / 3)) + offx;
            float py = (float)(j + (n % 3)) + offy;
            float qxf = floorf(px), qyf = floorf(py);
            int x0 = min(max((int)qxf, 0), HH - 1);
            int y0 = min(max((int)qyf, 0), WW - 1);
            int x1 = min(max((int)qxf + 1, 0), HH - 1);
            int y1 = min(max((int)qyf + 1, 0), WW - 1);
            float pxc = fminf(fmaxf(px, 0.f), (float)(HH - 1));
            float pyc = fminf(fmaxf(py, 0.f), (float)(WW - 1));
            float gx0 = 1.f + ((float)x0 - pxc);
            float gx1 = 1.f - ((float)x1 - pxc);
            float gy0 = 1.f + ((float)y0 - pyc);
            float gy1 = 1.f - ((float)y1 - pyc);
            float glt = gx0 * gy0, grb = gx1 * gy1;
            float glb = gx0 * gy1, grt = gx1 * gy0;
            int o00 = x0 * WW + y0, o11 = x1 * WW + y1;
            int o01 = x0 * WW + y1, o10 = x1 * WW + y0;
            const float* fc = fb + (h * 32) * HW;
#pragma unroll 4
            for (int cc = 0; cc < 32; ++cc) {
                float v = glt * fc[o00] + grb * fc[o11]
                        + glb * fc[o01] + grt * fc[o10];
                int ckl = cc * 9 + n;            // local ck within half
                unsigned int bits = __float_as_uint(v);
                unsigned int r = bits + 0x7fffu + ((bits >> 16) & 1u);  // RNE
                xs16[((ckl >> 1) * 64 + pos) * 2 + (ckl & 1)] =
                    (unsigned short)(r >> 16);
                fc += HW;
            }
        }
        __syncthreads();

        // ---- phase 2: acc[oo] += xs[ck][pos] * wt[ck][o0+oo] ----
        const float* wbase = wt + (h * 288) * 128 + o0;
        for (int ckp = 0; ckp < 144; ++ckp) {
            unsigned int u = xsp[ckp * 64 + lane];
            float x0 = __uint_as_float(u << 16);           // even ck
            float x1 = __uint_as_float(u & 0xffff0000u);   // odd ck
            const float* w0 = wbase + (ckp * 2) * 128;     // wave-uniform
            const float* w1 = w0 + 128;
#pragma unroll
            for (int oo = 0; oo < 32; ++oo) {
                acc[oo] = fmaf(x0, w0[oo], acc[oo]);
                acc[oo] = fmaf(x1, w1[oo], acc[oo]);
            }
        }
        __syncthreads();
    }

    // ---- epilogue ----
#pragma unroll
    for (int oo = 0; oo < 32; ++oo) {
        int o = o0 + oo;
        out[((b * OCC + o) * HH + i) * WW + j0 + lane] = acc[oo] + b_conv[o];
    }
}

extern "C" void kernel_launch(void* const* d_in, const int* in_sizes, int n_in,
                              void* d_out, int out_size, void* d_ws, size_t ws_size,
                              hipStream_t stream) {
    const float* feat   = (const float*)d_in[0];
    const float* w_p    = (const float*)d_in[1];
    const float* b_p    = (const float*)d_in[2];
    const float* w_conv = (const float*)d_in[3];
    const float* b_conv = (const float*)d_in[4];
    float* out = (float*)d_out;
    float* ws  = (float*)d_ws;

    float* off = ws + OFF_OFS;
    float* wpt = ws + WPT_OFS;
    float* wt  = ws + WT_OFS;

    hipLaunchKernelGGL(transpose_weights, dim3(329), dim3(256), 0, stream,
                       w_p, w_conv, ws);
    hipLaunchKernelGGL(offset_conv, dim3(NB * 128 * 2), dim3(256), 0, stream,
                       feat, b_p, wpt, off);
    hipLaunchKernelGGL(dcn_main, dim3(NB * 128 * 2), dim3(256), 0, stream,
                       feat, b_conv, off, wt, out);
}